// Round 5
// baseline (781.136 us; speedup 1.0000x reference)
//
#include <hip/hip_runtime.h>

#define NPTS   65536
#define DIM    128
#define KCODES 1024
#define BM     128      // points per argmin block
#define TILE_C 64       // codes per LDS tile (double-buffered)
#define NTHR   512

typedef short bf16x8 __attribute__((ext_vector_type(8)));
typedef float f32x4  __attribute__((ext_vector_type(4)));

__device__ __forceinline__ short f2bf(float f) {
    unsigned u = __builtin_bit_cast(unsigned, f);
    u = (u + 0x7fffu + ((u >> 16) & 1u)) >> 16;   // RNE
    return (short)u;
}
__device__ __forceinline__ float bf2f(short s) {
    unsigned u = ((unsigned)(unsigned short)s) << 16;
    return __builtin_bit_cast(float, u);
}
__device__ __forceinline__ void gload_lds16(const void* g, void* l) {
    __builtin_amdgcn_global_load_lds(
        (const __attribute__((address_space(1))) void*)g,
        (__attribute__((address_space(3))) void*)l, 16, 0, 0);
}

// ---------------- Kernel 0: halfnorm[c] = 0.5 * ||embed[c]||^2 (exact fp32) ----
__global__ __launch_bounds__(256)
void halfnorm_kernel(const float* __restrict__ embed, float* __restrict__ hn)
{
    const int w    = (blockIdx.x * blockDim.x + threadIdx.x) >> 6;
    const int lane = threadIdx.x & 63;
    if (w < KCODES) {
        float v0 = embed[(long)w * DIM + lane];
        float v1 = embed[(long)w * DIM + 64 + lane];
        float s  = v0 * v0 + v1 * v1;
        #pragma unroll
        for (int off = 32; off > 0; off >>= 1) s += __shfl_xor(s, off);
        if (lane == 0) hn[w] = 0.5f * s;
    }
}

// ---------------- Kernel P: pack codebook -> fragment-ordered bf16 hi/lo -------
// g: tc=g>>11 (tile of 64 codes), f=(g>>6)&31, l=g&63; f=h*16+nt*4+akk; l=hg*16+n
__global__ __launch_bounds__(256)
void pack_kernel(const float* __restrict__ embed, short* __restrict__ ebf,
                 int* __restrict__ ghist)
{
    const int g   = blockIdx.x * 256 + threadIdx.x;   // 0..32767
    if (g < KCODES) ghist[g] = 0;                     // zero global histogram
    const int tc  = g >> 11;
    const int f   = (g >> 6) & 31;
    const int l   = g & 63;
    const int h   = f >> 4;
    const int nt  = (f >> 2) & 3;
    const int akk = f & 3;
    const int hg  = l >> 4;
    const int n   = l & 15;
    const int c   = tc * TILE_C + nt * 16 + n;
    const int d0  = akk * 32 + hg * 8;
    const float* src = embed + (long)c * DIM + d0;
    float4 v0 = *reinterpret_cast<const float4*>(src);
    float4 v1 = *reinterpret_cast<const float4*>(src + 4);
    float vv[8] = {v0.x, v0.y, v0.z, v0.w, v1.x, v1.y, v1.z, v1.w};
    bf16x8 out;
    #pragma unroll
    for (int j = 0; j < 8; ++j) {
        short hi = f2bf(vv[j]);
        out[j] = h ? f2bf(vv[j] - bf2f(hi)) : hi;
    }
    *reinterpret_cast<bf16x8*>(ebf + (long)g * 8) = out;
}

// ---------------- Kernel 1: MFMA bf16x3 argmin + quantize + histogram ----------
__global__ __launch_bounds__(NTHR, 2)
void argmin_kernel(const float* __restrict__ x, const short* __restrict__ ebf,
                   const float* __restrict__ halfnorm, const float* __restrict__ embed,
                   int* __restrict__ ind, float* __restrict__ quant,
                   int* __restrict__ ghist)
{
    __shared__ short es[2][16384];      // 2 x 32 KB double-buffered tile
    __shared__ float hn_lds[KCODES];    // 4 KB
    __shared__ int   hist[KCODES];      // 4 KB
    __shared__ int   bidx[BM];

    const int t    = threadIdx.x;
    const int lane = t & 63;
    const int w    = t >> 6;           // wave 0..7, owns 16 points
    const int r16  = lane & 15;
    const int h4   = lane >> 4;
    const long xbase = (long)blockIdx.x * BM * DIM;
    const int  wp    = w * 16;

    for (int i = t; i < KCODES; i += NTHR) hist[i] = 0;

    // ---- A fragments: x row (wp+r16), hi/lo bf16 ----
    bf16x8 ahi[4], alo[4];
    {
        const long prow = xbase + (long)(wp + r16) * DIM;
        #pragma unroll
        for (int kk = 0; kk < 4; ++kk) {
            const float* s = x + prow + kk * 32 + h4 * 8;
            float4 u0 = *reinterpret_cast<const float4*>(s);
            float4 u1 = *reinterpret_cast<const float4*>(s + 4);
            float vv[8] = {u0.x, u0.y, u0.z, u0.w, u1.x, u1.y, u1.z, u1.w};
            #pragma unroll
            for (int j = 0; j < 8; ++j) {
                short hi = f2bf(vv[j]);
                ahi[kk][j] = hi;
                alo[kk][j] = f2bf(vv[j] - bf2f(hi));
            }
        }
    }
    if (t < 256) reinterpret_cast<float4*>(hn_lds)[t] =
                 reinterpret_cast<const float4*>(halfnorm)[t];

    // ---- prologue: stage tile 0 (wave w loads frags w*4..w*4+3, 1 KB each) ----
    #pragma unroll
    for (int i = 0; i < 4; ++i) {
        const int f = w * 4 + i;
        gload_lds16(ebf + (long)f * 512 + lane * 8, &es[0][f * 512]);
    }
    __syncthreads();   // drains vmcnt -> tile 0 resident; A/hn staged

    float bestv[4];
    int   besti[4];
    #pragma unroll
    for (int s = 0; s < 4; ++s) { bestv[s] = -1e30f; besti[s] = 0; }

    for (int tile = 0; tile < KCODES / TILE_C; ++tile) {
        // ---- issue next tile's stage first (latency hides under MFMA) ----
        if (tile + 1 < KCODES / TILE_C) {
            const long gbase = (long)(tile + 1) * 16384;
            #pragma unroll
            for (int i = 0; i < 4; ++i) {
                const int f = w * 4 + i;
                gload_lds16(ebf + gbase + f * 512 + lane * 8, &es[(tile + 1) & 1][f * 512]);
            }
        }

        const short* buf = es[tile & 1];
        f32x4 C[4];
        #pragma unroll
        for (int nt = 0; nt < 4; ++nt) C[nt] = (f32x4){0.f, 0.f, 0.f, 0.f};

        #pragma unroll
        for (int akk = 0; akk < 4; ++akk) {
            #pragma unroll
            for (int nt = 0; nt < 4; ++nt) {
                bf16x8 Bh = *reinterpret_cast<const bf16x8*>(buf + (nt * 4 + akk) * 512 + lane * 8);
                C[nt] = __builtin_amdgcn_mfma_f32_16x16x32_bf16(ahi[akk], Bh, C[nt], 0, 0, 0);
                C[nt] = __builtin_amdgcn_mfma_f32_16x16x32_bf16(alo[akk], Bh, C[nt], 0, 0, 0);
                bf16x8 Bl = *reinterpret_cast<const bf16x8*>(buf + (16 + nt * 4 + akk) * 512 + lane * 8);
                C[nt] = __builtin_amdgcn_mfma_f32_16x16x32_bf16(ahi[akk], Bl, C[nt], 0, 0, 0);
            }
        }

        #pragma unroll
        for (int nt = 0; nt < 4; ++nt) {
            const int   c   = tile * TILE_C + nt * 16 + r16;
            const float hnv = hn_lds[c];
            #pragma unroll
            for (int reg = 0; reg < 4; ++reg) {
                float sc = C[nt][reg] - hnv;
                if (sc > bestv[reg]) { bestv[reg] = sc; besti[reg] = c; }
            }
        }
        __syncthreads();   // vmcnt(0): next tile resident; cur tile readers done
    }

    // ---- butterfly reduce across 16 columns, tie -> smaller idx ----
    #pragma unroll
    for (int s = 0; s < 4; ++s) {
        float v = bestv[s];
        int   i = besti[s];
        #pragma unroll
        for (int off = 1; off < 16; off <<= 1) {
            float ov = __shfl_xor(v, off);
            int   oi = __shfl_xor(i, off);
            if (ov > v || (ov == v && oi < i)) { v = ov; i = oi; }
        }
        bestv[s] = v; besti[s] = i;
    }
    if (r16 == 0) {
        #pragma unroll
        for (int s = 0; s < 4; ++s) {
            int p = wp + h4 * 4 + s;
            bidx[p] = besti[s];
            ind[blockIdx.x * BM + p] = besti[s];
        }
    }
    __syncthreads();

    // ---- LDS histogram of this block's 128 assignments ----
    if (t < BM) atomicAdd(&hist[bidx[t]], 1);

    // ---- quantize: lane-contiguous gather-copy of embed[best] ----
    float4* dst = reinterpret_cast<float4*>(quant + xbase);
    #pragma unroll
    for (int i = 0; i < 8; ++i) {
        int idx = i * NTHR + t;          // 0..4095
        int p   = idx >> 5;
        int q   = idx & 31;
        int c   = bidx[p];
        dst[idx] = reinterpret_cast<const float4*>(embed + (long)c * DIM)[q];
    }

    __syncthreads();
    for (int i = t; i < KCODES; i += NTHR)
        if (hist[i]) atomicAdd(&ghist[i], hist[i]);
}

// ---------------- Kernel S: scan — offsets, cursors, ema_num_new ----------------
__global__ __launch_bounds__(1024)
void scan_kernel(const int* __restrict__ ghist, const float* __restrict__ ema_num,
                 float* __restrict__ ema_num_new, int* __restrict__ offset,
                 int* __restrict__ cursor)
{
    __shared__ int tmp[KCODES];
    const int t = threadIdx.x;
    const int v = ghist[t];
    ema_num_new[t] = ema_num[t] * 0.8f + 0.2f * (float)v;
    tmp[t] = v;
    __syncthreads();
    #pragma unroll
    for (int off = 1; off < KCODES; off <<= 1) {
        int u = (t >= off) ? tmp[t - off] : 0;
        __syncthreads();
        tmp[t] += u;
        __syncthreads();
    }
    const int excl = tmp[t] - v;   // exclusive prefix
    offset[t] = excl;
    cursor[t] = excl;
}

// ---------------- Kernel C: scatter point ids by code ----------------
__global__ __launch_bounds__(256)
void scatter_kernel(const int* __restrict__ ind, int* __restrict__ cursor,
                    int* __restrict__ sorted)
{
    const int p = blockIdx.x * 256 + threadIdx.x;
    const int c = ind[p];
    const int pos = atomicAdd(&cursor[c], 1);
    sorted[pos] = p;
}

// ---------------- Kernel G: per-code gather-sum + EMA epilogue ----------------
__global__ __launch_bounds__(128)
void sum_kernel(const float* __restrict__ x, const int* __restrict__ sorted,
                const int* __restrict__ offset, const int* __restrict__ ghist,
                const float* __restrict__ ema_embed, const float* __restrict__ ema_num_new,
                float* __restrict__ embed_new, float* __restrict__ ema_embed_new)
{
    const int c   = blockIdx.x;
    const int t   = threadIdx.x;    // dim 0..127
    const int beg = offset[c];
    const int n   = ghist[c];
    float acc = 0.f;
    for (int i = 0; i < n; ++i) {
        const int p = sorted[beg + i];
        acc += x[(long)p * DIM + t];
    }
    const float en = ema_num_new[c];
    const float ee = ema_embed[(long)c * DIM + t] * 0.8f + 0.2f * acc;
    ema_embed_new[(long)c * DIM + t] = ee;
    embed_new[(long)c * DIM + t]     = ee / en;
}

extern "C" void kernel_launch(void* const* d_in, const int* in_sizes, int n_in,
                              void* d_out, int out_size, void* d_ws, size_t ws_size,
                              hipStream_t stream)
{
    const float* x         = (const float*)d_in[0];
    const float* embed     = (const float*)d_in[1];
    const float* ema_embed = (const float*)d_in[2];
    const float* ema_num   = (const float*)d_in[3];

    float* out0 = (float*)d_out;            // quantize      (16*4096*128)
    float* out1 = out0 + 8388608;           // embed_new     (1024*128)
    float* out2 = out1 + 131072;            // ema_embed_new (1024*128)
    float* out3 = out2 + 131072;            // ema_num_new   (1024)

    char*  ws     = (char*)d_ws;
    float* hn     = (float*)ws;                     // 4 KB
    int*   ind    = (int*)(ws + 4096);              // 256 KB
    short* ebf    = (short*)(ws + 266240);          // 512 KB
    int*   ghist  = (int*)(ws + 790528);            // 4 KB
    int*   offset = (int*)(ws + 794624);            // 4 KB
    int*   cursor = (int*)(ws + 798720);            // 4 KB
    int*   sorted = (int*)(ws + 802816);            // 256 KB

    halfnorm_kernel<<<256, 256, 0, stream>>>(embed, hn);
    pack_kernel<<<128, 256, 0, stream>>>(embed, ebf, ghist);
    argmin_kernel<<<NPTS / BM, NTHR, 0, stream>>>(x, ebf, hn, embed, ind, out0, ghist);
    scan_kernel<<<1, 1024, 0, stream>>>(ghist, ema_num, out3, offset, cursor);
    scatter_kernel<<<NPTS / 256, 256, 0, stream>>>(ind, cursor, sorted);
    sum_kernel<<<KCODES, 128, 0, stream>>>(x, sorted, offset, ghist, ema_embed,
                                           out3, out1, out2);
}

// Round 6
// 112.211 us; speedup vs baseline: 6.9613x; 6.9613x over previous
//
#include <hip/hip_runtime.h>

#define NPTS   65536
#define DIM    128
#define KCODES 1024
#define BM     128      // points per argmin block
#define TILE_C 64       // codes per LDS tile (double-buffered)
#define NTHR   512

typedef short bf16x8 __attribute__((ext_vector_type(8)));
typedef float f32x4  __attribute__((ext_vector_type(4)));

__device__ __forceinline__ short f2bf(float f) {
    unsigned u = __builtin_bit_cast(unsigned, f);
    u = (u + 0x7fffu + ((u >> 16) & 1u)) >> 16;   // RNE
    return (short)u;
}
__device__ __forceinline__ float bf2f(short s) {
    unsigned u = ((unsigned)(unsigned short)s) << 16;
    return __builtin_bit_cast(float, u);
}
__device__ __forceinline__ void gload_lds16(const void* g, void* l) {
    __builtin_amdgcn_global_load_lds(
        (const __attribute__((address_space(1))) void*)g,
        (__attribute__((address_space(3))) void*)l, 16, 0, 0);
}

// ---------------- Kernel 0: halfnorm[c] = 0.5 * ||embed[c]||^2 (exact fp32) ----
__global__ __launch_bounds__(256)
void halfnorm_kernel(const float* __restrict__ embed, float* __restrict__ hn)
{
    const int w    = (blockIdx.x * blockDim.x + threadIdx.x) >> 6;
    const int lane = threadIdx.x & 63;
    if (w < KCODES) {
        float v0 = embed[(long)w * DIM + lane];
        float v1 = embed[(long)w * DIM + 64 + lane];
        float s  = v0 * v0 + v1 * v1;
        #pragma unroll
        for (int off = 32; off > 0; off >>= 1) s += __shfl_xor(s, off);
        if (lane == 0) hn[w] = 0.5f * s;
    }
}

// ---------------- Kernel P: pack codebook + init acc + zero hist ---------------
// g: tc=g>>11 (tile of 64 codes), f=(g>>6)&31, l=g&63; f=h*16+nt*4+akk; l=hg*16+n
__global__ __launch_bounds__(256)
void pack_kernel(const float* __restrict__ embed, short* __restrict__ ebf,
                 int* __restrict__ ghist, const float* __restrict__ ema_embed,
                 float* __restrict__ acc)
{
    const int g   = blockIdx.x * 256 + threadIdx.x;   // 0..32767
    if (g < KCODES) ghist[g] = 0;
    {   // init acc = 0.8 * ema_embed (float4 per thread covers all 131072)
        float4 e = reinterpret_cast<const float4*>(ema_embed)[g];
        float4 o = {0.8f * e.x, 0.8f * e.y, 0.8f * e.z, 0.8f * e.w};
        reinterpret_cast<float4*>(acc)[g] = o;
    }
    const int tc  = g >> 11;
    const int f   = (g >> 6) & 31;
    const int l   = g & 63;
    const int h   = f >> 4;
    const int nt  = (f >> 2) & 3;
    const int akk = f & 3;
    const int hg  = l >> 4;
    const int n   = l & 15;
    const int c   = tc * TILE_C + nt * 16 + n;
    const int d0  = akk * 32 + hg * 8;
    const float* src = embed + (long)c * DIM + d0;
    float4 v0 = *reinterpret_cast<const float4*>(src);
    float4 v1 = *reinterpret_cast<const float4*>(src + 4);
    float vv[8] = {v0.x, v0.y, v0.z, v0.w, v1.x, v1.y, v1.z, v1.w};
    bf16x8 out;
    #pragma unroll
    for (int j = 0; j < 8; ++j) {
        short hi = f2bf(vv[j]);
        out[j] = h ? f2bf(vv[j] - bf2f(hi)) : hi;
    }
    *reinterpret_cast<bf16x8*>(ebf + (long)g * 8) = out;
}

// ---------------- Kernel 1: MFMA bf16x3 argmin + quantize + histogram ----------
__global__ __launch_bounds__(NTHR, 2)
void argmin_kernel(const float* __restrict__ x, const short* __restrict__ ebf,
                   const float* __restrict__ halfnorm, const float* __restrict__ embed,
                   int* __restrict__ ind, float* __restrict__ quant,
                   int* __restrict__ ghist)
{
    __shared__ short es[2][16384];      // 2 x 32 KB double-buffered tile
    __shared__ float hn_lds[KCODES];    // 4 KB
    __shared__ int   hist[KCODES];      // 4 KB
    __shared__ int   bidx[BM];

    const int t    = threadIdx.x;
    const int lane = t & 63;
    const int w    = t >> 6;           // wave 0..7, owns 16 points
    const int r16  = lane & 15;
    const int h4   = lane >> 4;
    const long xbase = (long)blockIdx.x * BM * DIM;
    const int  wp    = w * 16;

    for (int i = t; i < KCODES; i += NTHR) hist[i] = 0;

    // ---- A fragments: x row (wp+r16), hi/lo bf16 ----
    bf16x8 ahi[4], alo[4];
    {
        const long prow = xbase + (long)(wp + r16) * DIM;
        #pragma unroll
        for (int kk = 0; kk < 4; ++kk) {
            const float* s = x + prow + kk * 32 + h4 * 8;
            float4 u0 = *reinterpret_cast<const float4*>(s);
            float4 u1 = *reinterpret_cast<const float4*>(s + 4);
            float vv[8] = {u0.x, u0.y, u0.z, u0.w, u1.x, u1.y, u1.z, u1.w};
            #pragma unroll
            for (int j = 0; j < 8; ++j) {
                short hi = f2bf(vv[j]);
                ahi[kk][j] = hi;
                alo[kk][j] = f2bf(vv[j] - bf2f(hi));
            }
        }
    }
    if (t < 256) reinterpret_cast<float4*>(hn_lds)[t] =
                 reinterpret_cast<const float4*>(halfnorm)[t];

    // ---- prologue: stage tile 0 (wave w loads frags w*4..w*4+3, 1 KB each) ----
    #pragma unroll
    for (int i = 0; i < 4; ++i) {
        const int f = w * 4 + i;
        gload_lds16(ebf + (long)f * 512 + lane * 8, &es[0][f * 512]);
    }
    __syncthreads();   // drains vmcnt -> tile 0 resident; A/hn staged

    float bestv[4];
    int   besti[4];
    #pragma unroll
    for (int s = 0; s < 4; ++s) { bestv[s] = -1e30f; besti[s] = 0; }

    for (int tile = 0; tile < KCODES / TILE_C; ++tile) {
        // ---- issue next tile's stage first (latency hides under MFMA) ----
        if (tile + 1 < KCODES / TILE_C) {
            const long gbase = (long)(tile + 1) * 16384;
            #pragma unroll
            for (int i = 0; i < 4; ++i) {
                const int f = w * 4 + i;
                gload_lds16(ebf + gbase + f * 512 + lane * 8, &es[(tile + 1) & 1][f * 512]);
            }
        }

        const short* buf = es[tile & 1];
        f32x4 C[4];
        #pragma unroll
        for (int nt = 0; nt < 4; ++nt) C[nt] = (f32x4){0.f, 0.f, 0.f, 0.f};

        #pragma unroll
        for (int akk = 0; akk < 4; ++akk) {
            #pragma unroll
            for (int nt = 0; nt < 4; ++nt) {
                bf16x8 Bh = *reinterpret_cast<const bf16x8*>(buf + (nt * 4 + akk) * 512 + lane * 8);
                C[nt] = __builtin_amdgcn_mfma_f32_16x16x32_bf16(ahi[akk], Bh, C[nt], 0, 0, 0);
                C[nt] = __builtin_amdgcn_mfma_f32_16x16x32_bf16(alo[akk], Bh, C[nt], 0, 0, 0);
                bf16x8 Bl = *reinterpret_cast<const bf16x8*>(buf + (16 + nt * 4 + akk) * 512 + lane * 8);
                C[nt] = __builtin_amdgcn_mfma_f32_16x16x32_bf16(ahi[akk], Bl, C[nt], 0, 0, 0);
            }
        }

        #pragma unroll
        for (int nt = 0; nt < 4; ++nt) {
            const int   c   = tile * TILE_C + nt * 16 + r16;
            const float hnv = hn_lds[c];
            #pragma unroll
            for (int reg = 0; reg < 4; ++reg) {
                float sc = C[nt][reg] - hnv;
                if (sc > bestv[reg]) { bestv[reg] = sc; besti[reg] = c; }
            }
        }
        __syncthreads();   // vmcnt(0): next tile resident; cur tile readers done
    }

    // ---- butterfly reduce across 16 columns, tie -> smaller idx ----
    #pragma unroll
    for (int s = 0; s < 4; ++s) {
        float v = bestv[s];
        int   i = besti[s];
        #pragma unroll
        for (int off = 1; off < 16; off <<= 1) {
            float ov = __shfl_xor(v, off);
            int   oi = __shfl_xor(i, off);
            if (ov > v || (ov == v && oi < i)) { v = ov; i = oi; }
        }
        bestv[s] = v; besti[s] = i;
    }
    if (r16 == 0) {
        #pragma unroll
        for (int s = 0; s < 4; ++s) {
            int p = wp + h4 * 4 + s;
            bidx[p] = besti[s];
            ind[blockIdx.x * BM + p] = besti[s];
        }
    }
    __syncthreads();

    // ---- LDS histogram of this block's 128 assignments ----
    if (t < BM) atomicAdd(&hist[bidx[t]], 1);

    // ---- quantize: lane-contiguous gather-copy of embed[best] ----
    float4* dst = reinterpret_cast<float4*>(quant + xbase);
    #pragma unroll
    for (int i = 0; i < 8; ++i) {
        int idx = i * NTHR + t;          // 0..4095
        int p   = idx >> 5;
        int q   = idx & 31;
        int c   = bidx[p];
        dst[idx] = reinterpret_cast<const float4*>(embed + (long)c * DIM)[q];
    }

    __syncthreads();
    for (int i = t; i < KCODES; i += NTHR)
        if (hist[i]) atomicAdd(&ghist[i], hist[i]);
}

// ---------------- Kernel S: scan — offsets, cursors, ema_num_new ----------------
__global__ __launch_bounds__(1024)
void scan_kernel(const int* __restrict__ ghist, const float* __restrict__ ema_num,
                 float* __restrict__ ema_num_new, int* __restrict__ cursor)
{
    __shared__ int tmp[KCODES];
    const int t = threadIdx.x;
    const int v = ghist[t];
    ema_num_new[t] = ema_num[t] * 0.8f + 0.2f * (float)v;
    tmp[t] = v;
    __syncthreads();
    #pragma unroll
    for (int off = 1; off < KCODES; off <<= 1) {
        int u = (t >= off) ? tmp[t - off] : 0;
        __syncthreads();
        tmp[t] += u;
        __syncthreads();
    }
    cursor[t] = tmp[t] - v;   // exclusive prefix
}

// ---------------- Kernel C: scatter point ids (and their codes) by code --------
__global__ __launch_bounds__(256)
void scatter_kernel(const int* __restrict__ ind, int* __restrict__ cursor,
                    int* __restrict__ sorted, int* __restrict__ scode)
{
    const int p = blockIdx.x * 256 + threadIdx.x;
    const int c = ind[p];
    const int pos = atomicAdd(&cursor[c], 1);
    sorted[pos] = p;
    scode[pos]  = c;
}

// ---------------- Kernel G: chunked run-sum over sorted order ------------------
// block b owns sorted[b*64 .. +63]; thread t = dim t; run-flush via atomicAdd.
__global__ __launch_bounds__(128)
void sum2_kernel(const float* __restrict__ x, const int* __restrict__ sorted,
                 const int* __restrict__ scode, float* __restrict__ acc)
{
    __shared__ int sp[64];
    __shared__ int sc[64];
    const int t = threadIdx.x;
    const int base = blockIdx.x * 64;
    if (t < 64) { sp[t] = sorted[base + t]; sc[t] = scode[base + t]; }
    __syncthreads();

    float a = 0.f;
    int cprev = sc[0];
    #pragma unroll 1
    for (int kk = 0; kk < 8; ++kk) {
        float v[8];
        #pragma unroll
        for (int i = 0; i < 8; ++i)
            v[i] = x[(long)sp[kk * 8 + i] * DIM + t];      // 8 independent 512B rows
        #pragma unroll
        for (int i = 0; i < 8; ++i) {
            const int c = sc[kk * 8 + i];                  // wave-uniform
            if (c != cprev) {
                atomicAdd(&acc[(long)cprev * DIM + t], 0.2f * a);
                a = 0.f; cprev = c;
            }
            a += v[i];
        }
    }
    atomicAdd(&acc[(long)cprev * DIM + t], 0.2f * a);
}

// ---------------- Kernel F: embed_new = ema_embed_new / ema_num_new ------------
__global__ __launch_bounds__(256)
void final_kernel(const float* __restrict__ acc, const float* __restrict__ ema_num_new,
                  float* __restrict__ embed_new)
{
    const int g = blockIdx.x * 256 + threadIdx.x;   // 0..32767 float4s
    float4 v = reinterpret_cast<const float4*>(acc)[g];
    const float en = ema_num_new[g >> 5];           // 32 float4s per code row
    float4 o = {v.x / en, v.y / en, v.z / en, v.w / en};
    reinterpret_cast<float4*>(embed_new)[g] = o;
}

extern "C" void kernel_launch(void* const* d_in, const int* in_sizes, int n_in,
                              void* d_out, int out_size, void* d_ws, size_t ws_size,
                              hipStream_t stream)
{
    const float* x         = (const float*)d_in[0];
    const float* embed     = (const float*)d_in[1];
    const float* ema_embed = (const float*)d_in[2];
    const float* ema_num   = (const float*)d_in[3];

    float* out0 = (float*)d_out;            // quantize      (16*4096*128)
    float* out1 = out0 + 8388608;           // embed_new     (1024*128)
    float* out2 = out1 + 131072;            // ema_embed_new (1024*128)
    float* out3 = out2 + 131072;            // ema_num_new   (1024)

    char*  ws     = (char*)d_ws;
    float* hn     = (float*)ws;                     // 4 KB
    int*   ind    = (int*)(ws + 4096);              // 256 KB
    short* ebf    = (short*)(ws + 266240);          // 512 KB
    int*   ghist  = (int*)(ws + 790528);            // 4 KB
    int*   cursor = (int*)(ws + 794624);            // 4 KB
    int*   sorted = (int*)(ws + 798720);            // 256 KB
    int*   scode  = (int*)(ws + 1060864);           // 256 KB

    halfnorm_kernel<<<256, 256, 0, stream>>>(embed, hn);
    pack_kernel<<<128, 256, 0, stream>>>(embed, ebf, ghist, ema_embed, out2);
    argmin_kernel<<<NPTS / BM, NTHR, 0, stream>>>(x, ebf, hn, embed, ind, out0, ghist);
    scan_kernel<<<1, 1024, 0, stream>>>(ghist, ema_num, out3, cursor);
    scatter_kernel<<<NPTS / 256, 256, 0, stream>>>(ind, cursor, sorted, scode);
    sum2_kernel<<<NPTS / 64, 128, 0, stream>>>(x, sorted, scode, out2);
    final_kernel<<<128, 256, 0, stream>>>(out2, out3, out1);
}